// Round 7
// baseline (111.226 us; speedup 1.0000x reference)
//
#include <hip/hip_runtime.h>
#include <hip/hip_bf16.h>

typedef unsigned short ushort_t;
typedef unsigned int uint_t;

#define CIN   128
#define COUT  256
#define HH    56
#define WW    56
#define HWSZ  3136            // 56*56
#define BATCH 16
#define NPIX  50176           // 16*3136
#define KTOT  1152            // 128*9

// LDS input patch: 4 pixel-rows (y0-1..y0+2) x 58 x-cols (halo) x 128 ci.
// ci-stride = 136 ushorts (68 uints): 16B-aligned cells, bank stride 4.
#define PROW_U 68             // uints per (pr,x) cell
#define PATCH_U (4 * 58 * 68) // 15776 uints = 63104 B (< 64KB static limit)

typedef __attribute__((ext_vector_type(8))) short bf16x8;
typedef __attribute__((ext_vector_type(4))) float f32x4;

__device__ __forceinline__ ushort_t f2bf(float v) {
    union { float f; uint_t u; } c; c.f = v;
    uint_t u = c.u;
    u += 0x7FFFu + ((u >> 16) & 1u);   // RNE; inputs finite
    return (ushort_t)(u >> 16);
}

__device__ __forceinline__ uint_t pk2bf(float lo, float hi) {
    __hip_bfloat162 h = __float22bfloat162_rn(make_float2(lo, hi));  // x->low ushort
    union { __hip_bfloat162 h; uint_t u; } c; c.h = h;
    return c.u;
}

// ---- weight prep: OIHW fp32 -> A2 fragment-order table (one co per block).
__global__ __launch_bounds__(256) void wprep(
    const float* __restrict__ weights, ushort_t* __restrict__ A2)
{
    __shared__ ushort_t lds_s[KTOT];
    const int tid = threadIdx.x;
    const int co  = blockIdx.x;
    const float* src = weights + (size_t)co * KTOT;
    #pragma unroll
    for (int k = 0; k < 5; ++k) {
        int idx = tid + k * 256;
        if (idx < KTOT) {
            int ci  = idx / 9;
            int pos = idx - ci * 9;
            lds_s[pos * 128 + ci] = f2bf(src[idx]);   // coalesced fp32 read
        }
    }
    __syncthreads();
    int mt  = co >> 6;
    int ii  = (co >> 4) & 3;
    int l16 = co & 15;
    if (tid < 144) {
        int s    = tid >> 2;
        int quad = tid & 3;
        uint4 v = *(const uint4*)&lds_s[(s >> 2) * 128 + (s & 3) * 32 + quad * 8];
        *(uint4*)(A2 + ((size_t)((mt * 36 + s) * 4 + ii) * 64 + quad * 16 + l16) * 8) = v;
    }
}

// ---- direct conv: block = 256co x 112pix (2 rows of one image), 4 waves (64co x 112px).
// Halo-only zeroing + staging (disjoint; single barrier), then a barrier-free,
// fully-unrolled 36-step K-loop with REGISTER PREFETCH of both A (global, dbuf)
// and B (LDS ds_read for step s+1 issued during step s's 28 MFMAs).
__global__ __launch_bounds__(256, 2) void conv_direct(
    const ushort_t* __restrict__ A2,
    const float* __restrict__ tensor,
    const float* __restrict__ bias,
    float* __restrict__ out)
{
    __shared__ __align__(16) uint_t patch[PATCH_U];
    const int tid  = threadIdx.x;
    const int wave = tid >> 6;
    const int lane = tid & 63;
    const int quad = lane >> 4;
    const int l16  = lane & 15;

    const int bn = blockIdx.x;            // [0,448): 28 blocks per image
    const int b  = bn / 28;
    const int y0 = (bn - b * 28) * 2;     // first output row of this block

    const uint4 z4 = make_uint4(0u, 0u, 0u, 0u);
    // ---- halo-only zeroing (x=0 and x=57 columns, all 4 patch rows) ----
    for (int t = tid; t < 204; t += 256) {        // 8 cells x 17 uint4
        int cell = t / 17, part = t - cell * 17;
        int pr = cell >> 1, xc = (cell & 1) * 57;
        *(uint4*)&patch[(pr * 58 + xc) * PROW_U + part * 4] = z4;
    }
    if (y0 == 0) {                                // row pr=0 (y=-1) invalid
        for (int t = tid; t < 986; t += 256) {    // 58 cells x 17 uint4
            int cell = t / 17, part = t - cell * 17;
            *(uint4*)&patch[cell * PROW_U + part * 4] = z4;
        }
    }
    if (y0 == 54) {                               // row pr=3 (y=56) invalid
        for (int t = tid; t < 986; t += 256) {
            int cell = t / 17, part = t - cell * 17;
            *(uint4*)&patch[(3 * 58 + cell) * PROW_U + part * 4] = z4;
        }
    }

    // ---- stage input rows y0-1..y0+2 (fp32 NCHW -> bf16 patch); disjoint from zeroing ----
    const float* src_b = tensor + (size_t)b * CIN * HWSZ;
    #pragma unroll
    for (int it = 0; it < 16; ++it) {
        int xq = tid & 15;
        int t2 = it * 16 + (tid >> 4);    // [0,256)
        int cp = t2 & 63;
        int pr = t2 >> 6;
        int y  = y0 - 1 + pr;
        if (xq < 14 && (uint_t)y < (uint_t)HH) {
            const float* s0 = src_b + (size_t)(2 * cp) * HWSZ + y * WW + xq * 4;
            float4 va = *(const float4*)s0;
            float4 vb = *(const float4*)(s0 + HWSZ);
            uint_t* dst = &patch[(pr * 58 + xq * 4 + 1) * PROW_U + cp];
            dst[0 * PROW_U] = pk2bf(va.x, vb.x);
            dst[1 * PROW_U] = pk2bf(va.y, vb.y);
            dst[2 * PROW_U] = pk2bf(va.z, vb.z);
            dst[3 * PROW_U] = pk2bf(va.w, vb.w);
        }
    }
    __syncthreads();      // the ONLY barrier

    // ---- B-fragment LDS base pointers (per j; quad ci-offset folded in) ----
    const ushort_t* patch_s = (const ushort_t*)patch;
    const ushort_t* bptr[7];
    #pragma unroll
    for (int j = 0; j < 7; ++j) {
        int p  = j * 16 + l16;            // block-local pixel [0,112)
        int ro = p / 56;
        int x  = p - ro * 56;
        bptr[j] = patch_s + (ro * 58 + x) * 136 + quad * 8;
    }

    // ---- A fragment stream base ----
    const ushort_t* aBase = A2 + ((size_t)(wave * 144) * 64 + lane) * 8;

    const f32x4 zero = {0.f, 0.f, 0.f, 0.f};
    f32x4 acc[4][7];
    #pragma unroll
    for (int i = 0; i < 4; ++i)
        #pragma unroll
        for (int j = 0; j < 7; ++j) acc[i][j] = zero;

    bf16x8 aCur[4], aNxt[4], bCur[7], bNxt[7];
    #pragma unroll
    for (int i = 0; i < 4; ++i) aCur[i] = *(const bf16x8*)(aBase + i * 512);
    // s=0: pos=0 (dy=-1,dx=-1) -> cell offset 0; cc=0
    #pragma unroll
    for (int j = 0; j < 7; ++j) bCur[j] = *(const bf16x8*)(bptr[j]);

    #pragma unroll
    for (int s = 0; s < 36; ++s) {
        if (s < 35) {
            const int s1   = s + 1;
            const int pos1 = s1 >> 2;
            const int cc1  = s1 & 3;
            const int off1 = ((pos1 / 3) * 58 + (pos1 % 3)) * 136 + cc1 * 32;  // compile-time
            #pragma unroll
            for (int i = 0; i < 4; ++i)
                aNxt[i] = *(const bf16x8*)(aBase + (size_t)(s1 * 4 + i) * 512);
            #pragma unroll
            for (int j = 0; j < 7; ++j)
                bNxt[j] = *(const bf16x8*)(bptr[j] + off1);
        }
        #pragma unroll
        for (int i = 0; i < 4; ++i)
            #pragma unroll
            for (int j = 0; j < 7; ++j)
                acc[i][j] = __builtin_amdgcn_mfma_f32_16x16x32_bf16(
                    aCur[i], bCur[j], acc[i][j], 0, 0, 0);
        #pragma unroll
        for (int i = 0; i < 4; ++i) aCur[i] = aNxt[i];   // renamed away under unroll
        #pragma unroll
        for (int j = 0; j < 7; ++j) bCur[j] = bNxt[j];
    }

    // ---- epilogue: row(quad*4+r)=cout, col(l16)=pixel (x-contiguous 64B segments) ----
    int opix[7];
    #pragma unroll
    for (int j = 0; j < 7; ++j) {
        int p  = j * 16 + l16;
        int ro = p / 56;
        int x  = p - ro * 56;
        opix[j] = (y0 + ro) * WW + x;
    }
    const size_t bout = (size_t)b * (COUT * HWSZ);
    #pragma unroll
    for (int i = 0; i < 4; ++i) {
        #pragma unroll
        for (int r = 0; r < 4; ++r) {
            int co = wave * 64 + i * 16 + quad * 4 + r;
            float bv = bias[co];
            size_t obase = bout + (size_t)co * HWSZ;
            #pragma unroll
            for (int j = 0; j < 7; ++j)
                out[obase + opix[j]] = acc[i][j][r] + bv;
        }
    }
}

// ---- fallback (only if workspace is too small): direct fp32 conv
__global__ void naive_conv(const float* __restrict__ in, const float* __restrict__ w,
                           const float* __restrict__ bias, float* __restrict__ out, int total) {
    int idx = blockIdx.x * 256 + threadIdx.x;
    if (idx >= total) return;
    int x = idx % WW; int t = idx / WW;
    int y = t % HH; t /= HH;
    int co = t % COUT; int b = t / COUT;
    float s = bias[co];
    const float* wr = w + (size_t)co * KTOT;
    for (int ci = 0; ci < CIN; ++ci) {
        const float* ir = in + (size_t)(b * CIN + ci) * HWSZ;
        for (int kh = 0; kh < 3; ++kh) {
            int yy = y + kh - 1;
            if ((uint_t)yy >= (uint_t)HH) continue;
            for (int kw = 0; kw < 3; ++kw) {
                int xx = x + kw - 1;
                if ((uint_t)xx >= (uint_t)WW) continue;
                s += ir[yy * WW + xx] * wr[ci * 9 + kh * 3 + kw];
            }
        }
    }
    out[idx] = s;
}

extern "C" void kernel_launch(void* const* d_in, const int* in_sizes, int n_in,
                              void* d_out, int out_size, void* d_ws, size_t ws_size,
                              hipStream_t stream) {
    const float* tensor  = (const float*)d_in[0];
    const float* weights = (const float*)d_in[1];
    const float* bias    = (const float*)d_in[2];
    float* out = (float*)d_out;

    const size_t A2_BYTES = (size_t)COUT * KTOT * 2;   // 589824

    if (ws_size >= A2_BYTES) {
        ushort_t* A2 = (ushort_t*)d_ws;
        wprep<<<COUT, 256, 0, stream>>>(weights, A2);
        conv_direct<<<NPIX / 112, 256, 0, stream>>>(A2, tensor, bias, out);
    } else {
        int total = BATCH * COUT * HWSZ;
        naive_conv<<<(total + 255) / 256, 256, 0, stream>>>(tensor, weights, bias, out, total);
    }
}